// Round 13
// baseline (206.571 us; speedup 1.0000x reference)
//
#include <hip/hip_runtime.h>
#include <hip/hip_bf16.h>
#include <math.h>

#define DIMC 384
#define NH 6
#define HD 64
#define MLPD 1536
#define BS 8
#define SEQ 1024
#define T_TOK (BS*SEQ)                  // 8192 tokens
#define TC ((size_t)T_TOK*DIMC)         // 3,145,728 elems
#define QK_SCALE 0.125f                 // 64^-0.5

typedef __bf16 bf16;
typedef bf16 bf16x4 __attribute__((ext_vector_type(4)));
typedef bf16 bf16x8 __attribute__((ext_vector_type(8)));
typedef float floatx4 __attribute__((ext_vector_type(4)));

// async global->LDS 16B (per-lane LDS dest must equal wave-uniform-base + lane*16)
__device__ __forceinline__ void async_cp16(const void* gsrc, void* ldst) {
    __builtin_amdgcn_global_load_lds(
        (const __attribute__((address_space(1))) unsigned int*)gsrc,
        (__attribute__((address_space(3))) unsigned int*)ldst,
        16, 0, 0);
}

// ---- merged: fp32->bf16 weight cvt (blocks 0..1727) | LN1 (blocks 1728..3775) ----
__global__ __launch_bounds__(256)
void prep_kernel(const float* __restrict__ s0, const float* __restrict__ s1,
                 const float* __restrict__ s2, const float* __restrict__ s3,
                 bf16* __restrict__ dst,
                 const float* __restrict__ x, const float* __restrict__ lw,
                 const float* __restrict__ lb, bf16* __restrict__ out) {
    if (blockIdx.x < 1728) {
        int i = blockIdx.x * 256 + threadIdx.x;   // i < 442368 float4 chunks
        const int n0 = 110592, n1 = 36864, n2 = 147456;   // float4 counts
        const float4* src; int j;
        if (i < n0)           { src = (const float4*)s0; j = i; }
        else if (i < n0+n1)   { src = (const float4*)s1; j = i - n0; }
        else if (i < n0+n1+n2){ src = (const float4*)s2; j = i - n0 - n1; }
        else                  { src = (const float4*)s3; j = i - n0 - n1 - n2; }
        float4 v = src[j];
        bf16x4 o; o[0] = (bf16)v.x; o[1] = (bf16)v.y; o[2] = (bf16)v.z; o[3] = (bf16)v.w;
        ((bf16x4*)dst)[i] = o;
    } else {
        int row = (blockIdx.x - 1728) * 4 + (threadIdx.x >> 6);
        int t = threadIdx.x & 63;
        const float* xr = x + (size_t)row * DIMC;
        float vals[6];
        float s = 0.f;
        #pragma unroll
        for (int i = 0; i < 6; i++) { vals[i] = xr[t + i*64]; s += vals[i]; }
        #pragma unroll
        for (int m = 32; m; m >>= 1) s += __shfl_xor(s, m);
        float mean = s * (1.0f / DIMC);
        float sq = 0.f;
        #pragma unroll
        for (int i = 0; i < 6; i++) { float d = vals[i] - mean; sq += d * d; }
        #pragma unroll
        for (int m = 32; m; m >>= 1) sq += __shfl_xor(sq, m);
        float rstd = rsqrtf(sq * (1.0f / DIMC) + 1e-5f);
        bf16* orow = out + (size_t)row * DIMC;
        #pragma unroll
        for (int i = 0; i < 6; i++) {
            int c = t + i*64;
            orow[c] = (bf16)((vals[i] - mean) * rstd * lw[c] + lb[c]);
        }
    }
}

// ---- fused: x1 = x + Pp + proj_b (write fp32 x1) ; h = LN2(x1) (write bf16) ----
// (proj is now KS=1 -> single exact bf16 partial)
__global__ __launch_bounds__(256)
void ln2_fused(const float* __restrict__ x, const bf16* __restrict__ p0,
               const float* __restrict__ pb,
               const float* __restrict__ w, const float* __restrict__ b,
               float* __restrict__ x1, bf16* __restrict__ h) {
    int row = blockIdx.x * 4 + (threadIdx.x >> 6);
    int t = threadIdx.x & 63;
    size_t base = (size_t)row * DIMC;
    float vals[6];
    float s = 0.f;
    #pragma unroll
    for (int i = 0; i < 6; i++) {
        int c = t + i*64;
        float v = x[base + c] + (float)p0[base + c] + pb[c];
        vals[i] = v; s += v;
    }
    #pragma unroll
    for (int m = 32; m; m >>= 1) s += __shfl_xor(s, m);
    float mean = s * (1.0f / DIMC);
    float sq = 0.f;
    #pragma unroll
    for (int i = 0; i < 6; i++) { float d = vals[i] - mean; sq += d * d; }
    #pragma unroll
    for (int m = 32; m; m >>= 1) sq += __shfl_xor(sq, m);
    float rstd = rsqrtf(sq * (1.0f / DIMC) + 1e-5f);
    #pragma unroll
    for (int i = 0; i < 6; i++) {
        int c = t + i*64;
        x1[base + c] = vals[i];
        h[base + c] = (bf16)((vals[i] - mean) * rstd * w[c] + b[c]);
    }
}

// ---------------- GEMM: C[M,N] = A[M,K] @ W[N,K]^T ----------------
// Round-13: split-K removed (it only existed to inflate tiny grids; with 8-wave
// blocks the grid is supplied by TM=64 for the N=384 GEMMs instead). EPI_RES
// fuses the old reduce4: out = x1 + b2 + acc, fp32 in-place (KS=1 -> exact).
// XCD decode generalized to NY = M/TM y-panels (NY8 = NY/8 = 1024/TM).
enum { EPI_NONE = 0, EPI_QKV = 1, EPI_GELU = 3, EPI_RES = 4 };

template<int EPI, int K, int KS, int NX, int TM, typename OutT>
__global__ __launch_bounds__(512)
void gemm_bt(const bf16* __restrict__ A, const bf16* __restrict__ W,
             const float* __restrict__ bias, OutT* out, int M, int N) {
    __shared__ __align__(16) bf16 Ash[2][TM*32];
    __shared__ __align__(16) bf16 Bsh[2][4096];
    constexpr int KB = K / KS;               // K extent per block
    constexpr int NK = KB / 32;              // k-steps
    constexpr int NY8 = 1024 / TM;           // (M/TM)/8 y-panel groups (M=8192)
    constexpr int ACC_M = TM / 32;           // 16-row subtiles per wave
    int L = blockIdx.x;                      // grid = (M/TM)*NX*KS
    int xcd = L & 7, ii = L >> 3;
    int ysub = ii % NY8, rest = ii / NY8;    // rest in [0, NX*KS)
    int bx = rest % NX, bz = rest / NX;
    int by = ysub * 8 + xcd;                 // y-panel pinned to xcd
    int tid = threadIdx.x;
    int lane = tid & 63, w = tid >> 6;
    int quad = lane >> 4, l16 = lane & 15;
    int wr = w >> 2, wc = w & 3;             // 2x4 wave layout
    int rbase = by * TM + wr * (TM/2);
    int cbase = bx * 128 + wc * 32;
    int kbase = bz * KB;
    const bf16* Ag1 = A + (size_t)(by*TM + (tid >> 2)) * K + kbase + (tid & 3) * 8;
    const bf16* Wg1 = W + (size_t)(bx*128 + (tid >> 2)) * K + kbase + (tid & 3) * 8;
    bf16* As1 = &Ash[0][tid * 8];            // valid only when tid < TM*4
    bf16* Bs1 = &Bsh[0][tid * 8];
    constexpr int ACHUNK = TM * 4;           // A chunks per tile (16B each)

    int arow = wr * (TM/2);                  // wave's row offset within tile
    int brow = wc * 32;

    // prologue: stage k-step 0 into buf 0
    if (TM == 128 || tid < ACHUNK) async_cp16(Ag1, As1);
    async_cp16(Wg1, Bs1);
    __syncthreads();                         // drains lds-DMA (vmcnt)

    floatx4 acc[ACC_M][2] = {};
    int buf = 0;
    #pragma unroll 2
    for (int kk = 0; kk < NK; kk++) {
        if (kk + 1 < NK) {                   // issue next step's staging first
            if (TM == 128 || tid < ACHUNK)
                async_cp16(Ag1 + (kk+1)*32, As1 + (buf ^ 1) * (TM*32));
            async_cp16(Wg1 + (kk+1)*32, Bs1 + (buf ^ 1) * 4096);
        }
        const bf16* Ab = Ash[buf];
        const bf16* Bb = Bsh[buf];
        bf16x8 a[ACC_M], bfr[2];
        #pragma unroll
        for (int tm = 0; tm < ACC_M; tm++)
            a[tm] = *(const bf16x8*)&Ab[(arow + tm*16 + l16) * 32 + quad*8];
        #pragma unroll
        for (int tn = 0; tn < 2; tn++)
            bfr[tn] = *(const bf16x8*)&Bb[(brow + tn*16 + l16) * 32 + quad*8];
        #pragma unroll
        for (int tm = 0; tm < ACC_M; tm++)
            #pragma unroll
            for (int tn = 0; tn < 2; tn++)
                acc[tm][tn] = __builtin_amdgcn_mfma_f32_16x16x32_bf16(a[tm], bfr[tn], acc[tm][tn], 0, 0, 0);
        __syncthreads();                     // reads done + next staging landed
        buf ^= 1;
    }

    #pragma unroll
    for (int tm = 0; tm < ACC_M; tm++)
        #pragma unroll
        for (int tn = 0; tn < 2; tn++) {
            if constexpr (EPI == EPI_QKV) {
                int colb = cbase + tn*16 + l16;       // 'which' uniform per 16-col subtile
                int which = colb / 384;
                int rowb = rbase + tm*16 + quad*4;
                int bb = rowb >> 10;
                if (which == 2) {
                    // V transposed: [B,H,D,N]; 4 consecutive n -> packed 8B store
                    int rem = colb - 768;
                    int hh = rem >> 6, d = rem & 63;
                    int n = rowb & 1023;
                    bf16x4 pk;
                    #pragma unroll
                    for (int r = 0; r < 4; r++) pk[r] = (bf16)acc[tm][tn][r];
                    *(bf16x4*)((bf16*)out + 2*TC + (((size_t)(bb*NH + hh) * HD + d) << 10) + n) = pk;
                } else {
                    int rem = colb - which*384;
                    int hh = rem >> 6, d = rem & 63;
                    #pragma unroll
                    for (int r = 0; r < 4; r++) {
                        int n = (rowb & 1023) + r;
                        ((bf16*)out)[(size_t)which*TC + (((size_t)(bb*NH + hh) * SEQ + n) << 6) + d]
                            = (bf16)acc[tm][tn][r];
                    }
                }
            } else if constexpr (EPI == EPI_NONE) {
                OutT* ob = out + (size_t)bz * M * N;
                #pragma unroll
                for (int r = 0; r < 4; r++) {
                    int row = rbase + tm*16 + quad*4 + r;
                    int col = cbase + tn*16 + l16;
                    ob[(size_t)row * N + col] = (OutT)acc[tm][tn][r];
                }
            } else if constexpr (EPI == EPI_RES) {
                // out = x1 + b2 + acc (fp32, in-place on out buffer; KS=1 exact)
                float* ob = (float*)out;
                #pragma unroll
                for (int r = 0; r < 4; r++) {
                    int row = rbase + tm*16 + quad*4 + r;
                    int col = cbase + tn*16 + l16;
                    size_t idx = (size_t)row * N + col;
                    ob[idx] = ob[idx] + bias[col] + acc[tm][tn][r];
                }
            } else {  // EPI_GELU
                #pragma unroll
                for (int r = 0; r < 4; r++) {
                    int row = rbase + tm*16 + quad*4 + r;
                    int col = cbase + tn*16 + l16;
                    float v = acc[tm][tn][r] + bias[col];
                    v = 0.5f * v * (1.0f + erff(v * 0.70710678118f));
                    out[(size_t)row * N + col] = (OutT)v;
                }
            }
        }
}

// ---------------- Fused L2Q attention (round 9 structure, unchanged) ----------------
// Flash-style: K/V^T tiles staged per-chunk via global_load_lds, double-buffered,
// staging issued BEFORE current-chunk compute, one barrier per chunk. P register-
// resident via permuted-K-row trick; XOR-swizzled chunks both sides; waves split q.
__global__ __launch_bounds__(256)
void attn_kernel(const bf16* __restrict__ q, const bf16* __restrict__ k,
                 const bf16* __restrict__ vt, const float* __restrict__ alpha,
                 const float* __restrict__ beta, const float* __restrict__ gamma,
                 bf16* __restrict__ attn_out) {
    // [buf][ K 64x64 | V^T 64x64 ] bf16, chunk-XOR-swizzled rows; 32 KB total
    __shared__ __align__(16) bf16 smem[2][8192];

    int L = blockIdx.x;
    int xcd = L & 7, slot = L >> 3;               // slot in [0,96)
    int qt = slot & 15;                           // 16 q-tiles of 64 rows
    int bh = xcd + ((slot >> 4) << 3);            // {xcd, xcd+8, ..., xcd+40}
    int bb = bh / NH, h = bh % NH;
    int q0 = qt * 64;
    int tid = threadIdx.x;
    int w = tid >> 6, lane = tid & 63, quad = lane >> 4, l16 = lane & 15;
    float av = alpha[h] * (QK_SCALE * QK_SCALE), bv = beta[h] * QK_SCALE, gv = gamma[h];
    const bf16* qb  = q  + (size_t)bh * SEQ * HD;
    const bf16* kb  = k  + (size_t)bh * SEQ * HD;
    const bf16* vtb = vt + (size_t)bh * HD * SEQ;

    // Q fragments (B operand): col l16 <-> q row q0 + w*16 + l16; loop-invariant
    bf16x8 qa[2];
    #pragma unroll
    for (int s = 0; s < 2; s++)
        qa[s] = *(const bf16x8*)(qb + (size_t)(q0 + w*16 + l16) * HD + s*32 + quad*8);

    floatx4 o[4] = {};                            // O[q=quad*4+r][d = dblk*16 + l16]
    float rsp = 0.f;                              // rowsum partial for q = l16
    int krow0 = ((l16 >> 2) << 3) + (l16 & 3);    // permuted K-row base (R8 trick)

    // staging: 2 calls x (K,V); i2 = call*256+tid; r=i2>>3, c=i2&7
    // keyK(r) = (r&3)|((r>>4&1)<<2)  (K reads: rows {0-3,8-11,16-19,24-27}+off -> 2-way)
    // keyV(r) = r&7                  (V reads: 16 consecutive rows -> 2-way)
    #define STAGE(CK, BUF)                                                              \
        {                                                                               \
            bf16* Kb_ = smem[BUF];                                                      \
            bf16* Vb_ = smem[BUF] + 4096;                                               \
            _Pragma("unroll")                                                           \
            for (int call = 0; call < 2; call++) {                                      \
                int i2 = call*256 + tid;                                                \
                int r_ = i2 >> 3, c_ = i2 & 7;                                          \
                int kk_ = (r_ & 3) | (((r_ >> 4) & 1) << 2);                            \
                async_cp16(kb  + (size_t)((CK) + r_) * HD + ((c_ ^ kk_) << 3),          \
                           Kb_ + i2*8);                                                 \
                async_cp16(vtb + (size_t)r_ * SEQ + (CK) + ((c_ ^ (r_ & 7)) << 3),      \
                           Vb_ + i2*8);                                                 \
            }                                                                           \
        }

    STAGE(0, 0);
    __syncthreads();                              // chunk 0 resident

    for (int c = 0; c < 16; c++) {
        int cur = c & 1;
        if (c < 15) STAGE((c+1)*64, cur ^ 1);     // issue next-chunk staging first
        const bf16* Kb = smem[cur];
        const bf16* Vb = smem[cur] + 4096;
        // ---- QK^T: 8 swizzled ds_read_b128 + 8 MFMA
        floatx4 sb[2][2] = {};
        #pragma unroll
        for (int s = 0; s < 2; s++)
            #pragma unroll
            for (int b = 0; b < 2; b++)
                #pragma unroll
                for (int j = 0; j < 2; j++) {
                    int g = b*32 + j*4 + krow0;
                    int kk = (g & 3) | (((g >> 4) & 1) << 2);
                    bf16x8 kf = *(const bf16x8*)(Kb + g*64 + (((s*4 + quad) ^ kk) << 3));
                    sb[b][j] = __builtin_amdgcn_mfma_f32_16x16x32_bf16(kf, qa[s], sb[b][j], 0, 0, 0);
                }
        // ---- quadratic relu + rowsum + pack to PV A-frags (all lane-local, R8-verified)
        bf16x8 pf[2];
        #pragma unroll
        for (int b = 0; b < 2; b++)
            #pragma unroll
            for (int j = 0; j < 2; j++)
                #pragma unroll
                for (int r = 0; r < 4; r++) {
                    float xx = sb[b][j][r];
                    float p = fmaxf((av*xx + bv)*xx + gv, 0.f);
                    rsp += p;
                    pf[b][j*4 + r] = (bf16)p;
                }
        // ---- PV: 8 swizzled ds_read_b128 + 8 MFMA
        #pragma unroll
        for (int b = 0; b < 2; b++)
            #pragma unroll
            for (int d = 0; d < 4; d++) {
                int dr = d*16 + l16;
                bf16x8 vf = *(const bf16x8*)(Vb + dr*64 + ((((b<<2) + quad) ^ (dr & 7)) << 3));
                o[d] = __builtin_amdgcn_mfma_f32_16x16x32_bf16(pf[b], vf, o[d], 0, 0, 0);
            }
        if (c < 15) __syncthreads();              // buf reads done + next staging done
    }

    // ---- rowsum: quad-reduce (all lanes then hold rs(q=l16)), shfl-broadcast
    rsp += __shfl_xor(rsp, 16);
    rsp += __shfl_xor(rsp, 32);
    float rsd[4];
    #pragma unroll
    for (int r = 0; r < 4; r++)
        rsd[r] = __shfl(rsp, quad*4 + r) + 1e-6f; // lane quad*4+r holds rs for that q
    // ---- divide + store (wave fully owns its 16 q rows x 64 d)
    #pragma unroll
    for (int d = 0; d < 4; d++)
        #pragma unroll
        for (int r = 0; r < 4; r++) {
            int n = q0 + w*16 + quad*4 + r;
            attn_out[((size_t)(bb*SEQ + n)) * DIMC + h*HD + d*16 + l16] =
                (bf16)(o[d][r] / rsd[r]);
        }
    #undef STAGE
}

// ---------------- driver ----------------
extern "C" void kernel_launch(void* const* d_in, const int* in_sizes, int n_in,
                              void* d_out, int out_size, void* d_ws, size_t ws_size,
                              hipStream_t stream) {
    const float* x      = (const float*)d_in[0];
    const float* qkv_w  = (const float*)d_in[1];
    const float* proj_w = (const float*)d_in[2];
    const float* proj_b = (const float*)d_in[3];
    const float* alpha  = (const float*)d_in[4];
    const float* beta   = (const float*)d_in[5];
    const float* gamma  = (const float*)d_in[6];
    const float* ln1_w  = (const float*)d_in[7];
    const float* ln1_b  = (const float*)d_in[8];
    const float* ln2_w  = (const float*)d_in[9];
    const float* ln2_b  = (const float*)d_in[10];
    const float* w1     = (const float*)d_in[11];
    const float* b1     = (const float*)d_in[12];
    const float* w2     = (const float*)d_in[13];
    const float* b2     = (const float*)d_in[14];
    float* out = (float*)d_out;           // fp32 output; also doubles as x1 buffer

    // ws layout (Pm gone; Pp now 1*TC)
    char* base = (char*)d_ws;
    bf16* wq_bf = (bf16*)base;                 // 1152x384
    bf16* wp_bf = wq_bf + 442368;              // 384x384
    bf16* w1_bf = wq_bf + 589824;              // 1536x384
    bf16* w2_bf = wq_bf + 1179648;             // 384x1536
    bf16* h      = (bf16*)(base + 3538944);
    bf16* qkv    = (bf16*)(base + 9830400);
    bf16* attn_o = (bf16*)(base + 28704768);
    bf16* m      = qkv;                        // overlays qkv+attn_o (both dead by mlp1)
    bf16* Pp     = (bf16*)(base + 34996224);   // 1*TC (proj output, exact)

    prep_kernel<<<1728 + T_TOK/4, 256, 0, stream>>>(
        qkv_w, proj_w, w1, w2, wq_bf, x, ln1_w, ln1_b, h);
    gemm_bt<EPI_QKV, 384, 1, 9, 128, bf16><<<64*9, 512, 0, stream>>>(
        h, wq_bf, nullptr, qkv, T_TOK, 1152);
    attn_kernel<<<768, 256, 0, stream>>>(
        qkv, qkv + TC, qkv + 2*TC, alpha, beta, gamma, attn_o);
    gemm_bt<EPI_NONE, 384, 1, 3, 64, bf16><<<128*3, 512, 0, stream>>>(
        attn_o, wp_bf, nullptr, Pp, T_TOK, DIMC);
    ln2_fused<<<T_TOK/4, 256, 0, stream>>>(x, Pp, proj_b, ln2_w, ln2_b, out, h);
    gemm_bt<EPI_GELU, 384, 1, 12, 128, bf16><<<64*12, 512, 0, stream>>>(
        h, w1_bf, b1, m, T_TOK, MLPD);
    gemm_bt<EPI_RES, 1536, 1, 3, 64, float><<<128*3, 512, 0, stream>>>(
        m, w2_bf, b2, out, T_TOK, DIMC);
}

// Round 14
// 197.078 us; speedup vs baseline: 1.0482x; 1.0482x over previous
//
#include <hip/hip_runtime.h>
#include <hip/hip_bf16.h>
#include <math.h>

#define DIMC 384
#define NH 6
#define HD 64
#define MLPD 1536
#define BS 8
#define SEQ 1024
#define T_TOK (BS*SEQ)                  // 8192 tokens
#define TC ((size_t)T_TOK*DIMC)         // 3,145,728 elems
#define QK_SCALE 0.125f                 // 64^-0.5

typedef __bf16 bf16;
typedef bf16 bf16x4 __attribute__((ext_vector_type(4)));
typedef bf16 bf16x8 __attribute__((ext_vector_type(8)));
typedef float floatx4 __attribute__((ext_vector_type(4)));

// async global->LDS 16B (per-lane LDS dest must equal wave-uniform-base + lane*16)
__device__ __forceinline__ void async_cp16(const void* gsrc, void* ldst) {
    __builtin_amdgcn_global_load_lds(
        (const __attribute__((address_space(1))) unsigned int*)gsrc,
        (__attribute__((address_space(3))) unsigned int*)ldst,
        16, 0, 0);
}

// ---- merged: fp32->bf16 weight cvt (blocks 0..1727) | LN1 (blocks 1728..3775) ----
__global__ __launch_bounds__(256)
void prep_kernel(const float* __restrict__ s0, const float* __restrict__ s1,
                 const float* __restrict__ s2, const float* __restrict__ s3,
                 bf16* __restrict__ dst,
                 const float* __restrict__ x, const float* __restrict__ lw,
                 const float* __restrict__ lb, bf16* __restrict__ out) {
    if (blockIdx.x < 1728) {
        int i = blockIdx.x * 256 + threadIdx.x;   // i < 442368 float4 chunks
        const int n0 = 110592, n1 = 36864, n2 = 147456;   // float4 counts
        const float4* src; int j;
        if (i < n0)           { src = (const float4*)s0; j = i; }
        else if (i < n0+n1)   { src = (const float4*)s1; j = i - n0; }
        else if (i < n0+n1+n2){ src = (const float4*)s2; j = i - n0 - n1; }
        else                  { src = (const float4*)s3; j = i - n0 - n1 - n2; }
        float4 v = src[j];
        bf16x4 o; o[0] = (bf16)v.x; o[1] = (bf16)v.y; o[2] = (bf16)v.z; o[3] = (bf16)v.w;
        ((bf16x4*)dst)[i] = o;
    } else {
        int row = (blockIdx.x - 1728) * 4 + (threadIdx.x >> 6);
        int t = threadIdx.x & 63;
        const float* xr = x + (size_t)row * DIMC;
        float vals[6];
        float s = 0.f;
        #pragma unroll
        for (int i = 0; i < 6; i++) { vals[i] = xr[t + i*64]; s += vals[i]; }
        #pragma unroll
        for (int m = 32; m; m >>= 1) s += __shfl_xor(s, m);
        float mean = s * (1.0f / DIMC);
        float sq = 0.f;
        #pragma unroll
        for (int i = 0; i < 6; i++) { float d = vals[i] - mean; sq += d * d; }
        #pragma unroll
        for (int m = 32; m; m >>= 1) sq += __shfl_xor(sq, m);
        float rstd = rsqrtf(sq * (1.0f / DIMC) + 1e-5f);
        bf16* orow = out + (size_t)row * DIMC;
        #pragma unroll
        for (int i = 0; i < 6; i++) {
            int c = t + i*64;
            orow[c] = (bf16)((vals[i] - mean) * rstd * lw[c] + lb[c]);
        }
    }
}

// ---- fused: x1 = x + Pp0 + Pp1 + proj_b (write fp32 x1) ; h = LN2(x1) (write bf16) ----
__global__ __launch_bounds__(256)
void ln2_fused(const float* __restrict__ x, const bf16* __restrict__ p0,
               const bf16* __restrict__ p1, const float* __restrict__ pb,
               const float* __restrict__ w, const float* __restrict__ b,
               float* __restrict__ x1, bf16* __restrict__ h) {
    int row = blockIdx.x * 4 + (threadIdx.x >> 6);
    int t = threadIdx.x & 63;
    size_t base = (size_t)row * DIMC;
    float vals[6];
    float s = 0.f;
    #pragma unroll
    for (int i = 0; i < 6; i++) {
        int c = t + i*64;
        float v = x[base + c] + (float)p0[base + c] + (float)p1[base + c] + pb[c];
        vals[i] = v; s += v;
    }
    #pragma unroll
    for (int m = 32; m; m >>= 1) s += __shfl_xor(s, m);
    float mean = s * (1.0f / DIMC);
    float sq = 0.f;
    #pragma unroll
    for (int i = 0; i < 6; i++) { float d = vals[i] - mean; sq += d * d; }
    #pragma unroll
    for (int m = 32; m; m >>= 1) sq += __shfl_xor(sq, m);
    float rstd = rsqrtf(sq * (1.0f / DIMC) + 1e-5f);
    #pragma unroll
    for (int i = 0; i < 6; i++) {
        int c = t + i*64;
        x1[base + c] = vals[i];
        h[base + c] = (bf16)((vals[i] - mean) * rstd * w[c] + b[c]);
    }
}

// ---- final: out = x1 + b2 + Pm0+Pm1+Pm2+Pm3 (bf16 partials), float4-vectorized ----
__global__ __launch_bounds__(256)
void reduce4(float* __restrict__ xo, const bf16* __restrict__ p0, const bf16* __restrict__ p1,
             const bf16* __restrict__ p2, const bf16* __restrict__ p3,
             const float* __restrict__ b2) {
    int i = blockIdx.x * 256 + threadIdx.x;   // float4 index, < TC/4
    float4 v = ((const float4*)xo)[i];
    int c = (i % 96) * 4;
    float4 bb = *(const float4*)(b2 + c);
    bf16x4 a0 = ((const bf16x4*)p0)[i], a1 = ((const bf16x4*)p1)[i];
    bf16x4 a2 = ((const bf16x4*)p2)[i], a3 = ((const bf16x4*)p3)[i];
    v.x += bb.x + (float)a0[0] + (float)a1[0] + (float)a2[0] + (float)a3[0];
    v.y += bb.y + (float)a0[1] + (float)a1[1] + (float)a2[1] + (float)a3[1];
    v.z += bb.z + (float)a0[2] + (float)a1[2] + (float)a2[2] + (float)a3[2];
    v.w += bb.w + (float)a0[3] + (float)a1[3] + (float)a2[3] + (float)a3[3];
    ((float4*)xo)[i] = v;
}

// ---------------- GEMM: C[M,N] = A[M,K] @ W[N,K]^T ----------------
// Round-14: R12 structure (128x128 tile, 8 waves, split-K, XCD decode) + T4
// counted-vmcnt 3-buffer pipeline. Old: __syncthreads per k-step drains vmcnt(0),
// re-exposing next-tile DMA latency. New: depth-2 prefetch; per step
// `s_waitcnt vmcnt(2); s_barrier` (one asm, "memory" clobber -- ds_reads can't
// hoist past it). In-order retirement: outstanding = {kk,kk+1} stages x2 loads;
// vmcnt(2) retires exactly kk. WAR-safe: stage(kk+2) overwrites the buffer whose
// reads drained before the iter-kk barrier. LDS 48KB -> 3 blocks/CU cap (threads
// cap 4; binding constraint ~unchanged).
enum { EPI_NONE = 0, EPI_QKV = 1, EPI_GELU = 3 };

template<int EPI, int K, int KS, int NX, typename OutT>
__global__ __launch_bounds__(512)
void gemm_bt(const bf16* __restrict__ A, const bf16* __restrict__ W,
             const float* __restrict__ bias, OutT* out, int M, int N) {
    __shared__ __align__(16) bf16 Ash[3][4096];
    __shared__ __align__(16) bf16 Bsh[3][4096];
    constexpr int KB = K / KS;               // K extent per block
    constexpr int NK = KB / 32;              // k-steps (>= 6 in all uses)
    int L = blockIdx.x;                      // grid = 64*NX*KS
    int xcd = L & 7, ii = L >> 3;
    int ysub = ii & 7, rest = ii >> 3;       // rest in [0, NX*KS)
    int bx = rest % NX, bz = rest / NX;
    int by = ysub * 8 + xcd;                 // y-panel pinned to xcd
    int tid = threadIdx.x;
    int lane = tid & 63, w = tid >> 6;
    int quad = lane >> 4, l16 = lane & 15;
    int wr = w >> 2, wc = w & 3;             // 2x4 wave layout
    int rbase = by * 128 + wr * 64;
    int cbase = bx * 128 + wc * 32;
    int kbase = bz * KB;
    const bf16* Ag1 = A + (size_t)(by*128 + (tid >> 2)) * K + kbase + (tid & 3) * 8;
    const bf16* Wg1 = W + (size_t)(bx*128 + (tid >> 2)) * K + kbase + (tid & 3) * 8;

    int arow = wr * 64;                      // wave's row offset within tile
    int brow = wc * 32;

    #define GSTAGE(KK, B) { async_cp16(Ag1 + (KK)*32, &Ash[B][tid*8]); \
                            async_cp16(Wg1 + (KK)*32, &Bsh[B][tid*8]); }
    GSTAGE(0, 0);
    GSTAGE(1, 1);

    floatx4 acc[4][2] = {};
    #pragma unroll 3
    for (int kk = 0; kk < NK; kk++) {
        if (kk + 1 < NK)
            asm volatile("s_waitcnt vmcnt(2)\n\ts_barrier" ::: "memory");
        else
            asm volatile("s_waitcnt vmcnt(0)\n\ts_barrier" ::: "memory");
        if (kk + 2 < NK) GSTAGE(kk+2, (kk+2)%3);
        const bf16* Ab = Ash[kk%3];
        const bf16* Bb = Bsh[kk%3];
        bf16x8 a[4], bfr[2];
        #pragma unroll
        for (int tm = 0; tm < 4; tm++)
            a[tm] = *(const bf16x8*)&Ab[(arow + tm*16 + l16) * 32 + quad*8];
        #pragma unroll
        for (int tn = 0; tn < 2; tn++)
            bfr[tn] = *(const bf16x8*)&Bb[(brow + tn*16 + l16) * 32 + quad*8];
        #pragma unroll
        for (int tm = 0; tm < 4; tm++)
            #pragma unroll
            for (int tn = 0; tn < 2; tn++)
                acc[tm][tn] = __builtin_amdgcn_mfma_f32_16x16x32_bf16(a[tm], bfr[tn], acc[tm][tn], 0, 0, 0);
    }
    #undef GSTAGE

    #pragma unroll
    for (int tm = 0; tm < 4; tm++)
        #pragma unroll
        for (int tn = 0; tn < 2; tn++) {
            if constexpr (EPI == EPI_QKV) {
                int colb = cbase + tn*16 + l16;       // 'which' uniform per 16-col subtile
                int which = colb / 384;
                int rowb = rbase + tm*16 + quad*4;
                int bb = rowb >> 10;
                if (which == 2) {
                    // V transposed: [B,H,D,N]; 4 consecutive n -> packed 8B store
                    int rem = colb - 768;
                    int hh = rem >> 6, d = rem & 63;
                    int n = rowb & 1023;
                    bf16x4 pk;
                    #pragma unroll
                    for (int r = 0; r < 4; r++) pk[r] = (bf16)acc[tm][tn][r];
                    *(bf16x4*)((bf16*)out + 2*TC + (((size_t)(bb*NH + hh) * HD + d) << 10) + n) = pk;
                } else {
                    int rem = colb - which*384;
                    int hh = rem >> 6, d = rem & 63;
                    #pragma unroll
                    for (int r = 0; r < 4; r++) {
                        int n = (rowb & 1023) + r;
                        ((bf16*)out)[(size_t)which*TC + (((size_t)(bb*NH + hh) * SEQ + n) << 6) + d]
                            = (bf16)acc[tm][tn][r];
                    }
                }
            } else if constexpr (EPI == EPI_NONE) {
                OutT* ob = out + (size_t)bz * M * N;
                #pragma unroll
                for (int r = 0; r < 4; r++) {
                    int row = rbase + tm*16 + quad*4 + r;
                    int col = cbase + tn*16 + l16;
                    ob[(size_t)row * N + col] = (OutT)acc[tm][tn][r];
                }
            } else {  // EPI_GELU
                #pragma unroll
                for (int r = 0; r < 4; r++) {
                    int row = rbase + tm*16 + quad*4 + r;
                    int col = cbase + tn*16 + l16;
                    float v = acc[tm][tn][r] + bias[col];
                    v = 0.5f * v * (1.0f + erff(v * 0.70710678118f));
                    out[(size_t)row * N + col] = (OutT)v;
                }
            }
        }
}

// ---------------- Fused L2Q attention (R9 structure + T4 counted-vmcnt) ----------------
// Flash-style LDS staging, now 3-buffer depth-2: stage c+2 each iter; per-iter
// `s_waitcnt vmcnt(4); s_barrier` (4 DMA loads/thread/stage; outstanding {c,c+1}
// = 8 -> vmcnt(4) retires exactly c). P register-resident (permuted-K-row);
// XOR-swizzled chunks both sides; waves split q. LDS 48KB -> 3 blocks/CU = grid.
__global__ __launch_bounds__(256)
void attn_kernel(const bf16* __restrict__ q, const bf16* __restrict__ k,
                 const bf16* __restrict__ vt, const float* __restrict__ alpha,
                 const float* __restrict__ beta, const float* __restrict__ gamma,
                 bf16* __restrict__ attn_out) {
    // [buf][ K 64x64 | V^T 64x64 ] bf16, chunk-XOR-swizzled rows; 48 KB total
    __shared__ __align__(16) bf16 smem[3][8192];

    int L = blockIdx.x;
    int xcd = L & 7, slot = L >> 3;               // slot in [0,96)
    int qt = slot & 15;                           // 16 q-tiles of 64 rows
    int bh = xcd + ((slot >> 4) << 3);            // {xcd, xcd+8, ..., xcd+40}
    int bb = bh / NH, h = bh % NH;
    int q0 = qt * 64;
    int tid = threadIdx.x;
    int w = tid >> 6, lane = tid & 63, quad = lane >> 4, l16 = lane & 15;
    float av = alpha[h] * (QK_SCALE * QK_SCALE), bv = beta[h] * QK_SCALE, gv = gamma[h];
    const bf16* qb  = q  + (size_t)bh * SEQ * HD;
    const bf16* kb  = k  + (size_t)bh * SEQ * HD;
    const bf16* vtb = vt + (size_t)bh * HD * SEQ;

    // Q fragments (B operand): col l16 <-> q row q0 + w*16 + l16; loop-invariant
    bf16x8 qa[2];
    #pragma unroll
    for (int s = 0; s < 2; s++)
        qa[s] = *(const bf16x8*)(qb + (size_t)(q0 + w*16 + l16) * HD + s*32 + quad*8);

    floatx4 o[4] = {};                            // O[q=quad*4+r][d = dblk*16 + l16]
    float rsp = 0.f;                              // rowsum partial for q = l16
    int krow0 = ((l16 >> 2) << 3) + (l16 & 3);    // permuted K-row base (R8 trick)

    // staging: 2 calls x (K,V); i2 = call*256+tid; r=i2>>3, c=i2&7
    // keyK(r) = (r&3)|((r>>4&1)<<2); keyV(r) = r&7 (2-way = free)
    #define STAGE(CK, BUF)                                                              \
        {                                                                               \
            bf16* Kb_ = smem[BUF];                                                      \
            bf16* Vb_ = smem[BUF] + 4096;                                               \
            _Pragma("unroll")                                                           \
            for (int call = 0; call < 2; call++) {                                      \
                int i2 = call*256 + tid;                                                \
                int r_ = i2 >> 3, c_ = i2 & 7;                                          \
                int kk_ = (r_ & 3) | (((r_ >> 4) & 1) << 2);                            \
                async_cp16(kb  + (size_t)((CK) + r_) * HD + ((c_ ^ kk_) << 3),          \
                           Kb_ + i2*8);                                                 \
                async_cp16(vtb + (size_t)r_ * SEQ + (CK) + ((c_ ^ (r_ & 7)) << 3),      \
                           Vb_ + i2*8);                                                 \
            }                                                                           \
        }

    STAGE(0, 0);
    STAGE(64, 1);

    for (int c = 0; c < 16; c++) {
        if (c + 1 < 16)
            asm volatile("s_waitcnt vmcnt(4)\n\ts_barrier" ::: "memory");
        else
            asm volatile("s_waitcnt vmcnt(0)\n\ts_barrier" ::: "memory");
        if (c + 2 < 16) STAGE((c+2)*64, (c+2)%3);
        const bf16* Kb = smem[c%3];
        const bf16* Vb = smem[c%3] + 4096;
        // ---- QK^T: 8 swizzled ds_read_b128 + 8 MFMA
        floatx4 sb[2][2] = {};
        #pragma unroll
        for (int s = 0; s < 2; s++)
            #pragma unroll
            for (int b = 0; b < 2; b++)
                #pragma unroll
                for (int j = 0; j < 2; j++) {
                    int g = b*32 + j*4 + krow0;
                    int kk = (g & 3) | (((g >> 4) & 1) << 2);
                    bf16x8 kf = *(const bf16x8*)(Kb + g*64 + (((s*4 + quad) ^ kk) << 3));
                    sb[b][j] = __builtin_amdgcn_mfma_f32_16x16x32_bf16(kf, qa[s], sb[b][j], 0, 0, 0);
                }
        // ---- quadratic relu + rowsum + pack to PV A-frags (all lane-local, R8-verified)
        bf16x8 pf[2];
        #pragma unroll
        for (int b = 0; b < 2; b++)
            #pragma unroll
            for (int j = 0; j < 2; j++)
                #pragma unroll
                for (int r = 0; r < 4; r++) {
                    float xx = sb[b][j][r];
                    float p = fmaxf((av*xx + bv)*xx + gv, 0.f);
                    rsp += p;
                    pf[b][j*4 + r] = (bf16)p;
                }
        // ---- PV: 8 swizzled ds_read_b128 + 8 MFMA
        #pragma unroll
        for (int b = 0; b < 2; b++)
            #pragma unroll
            for (int d = 0; d < 4; d++) {
                int dr = d*16 + l16;
                bf16x8 vf = *(const bf16x8*)(Vb + dr*64 + ((((b<<2) + quad) ^ (dr & 7)) << 3));
                o[d] = __builtin_amdgcn_mfma_f32_16x16x32_bf16(pf[b], vf, o[d], 0, 0, 0);
            }
    }

    // ---- rowsum: quad-reduce (all lanes then hold rs(q=l16)), shfl-broadcast
    rsp += __shfl_xor(rsp, 16);
    rsp += __shfl_xor(rsp, 32);
    float rsd[4];
    #pragma unroll
    for (int r = 0; r < 4; r++)
        rsd[r] = __shfl(rsp, quad*4 + r) + 1e-6f; // lane quad*4+r holds rs for that q
    // ---- divide + store (wave fully owns its 16 q rows x 64 d)
    #pragma unroll
    for (int d = 0; d < 4; d++)
        #pragma unroll
        for (int r = 0; r < 4; r++) {
            int n = q0 + w*16 + quad*4 + r;
            attn_out[((size_t)(bb*SEQ + n)) * DIMC + h*HD + d*16 + l16] =
                (bf16)(o[d][r] / rsd[r]);
        }
    #undef STAGE
}

// ---------------- driver ----------------
extern "C" void kernel_launch(void* const* d_in, const int* in_sizes, int n_in,
                              void* d_out, int out_size, void* d_ws, size_t ws_size,
                              hipStream_t stream) {
    const float* x      = (const float*)d_in[0];
    const float* qkv_w  = (const float*)d_in[1];
    const float* proj_w = (const float*)d_in[2];
    const float* proj_b = (const float*)d_in[3];
    const float* alpha  = (const float*)d_in[4];
    const float* beta   = (const float*)d_in[5];
    const float* gamma  = (const float*)d_in[6];
    const float* ln1_w  = (const float*)d_in[7];
    const float* ln1_b  = (const float*)d_in[8];
    const float* ln2_w  = (const float*)d_in[9];
    const float* ln2_b  = (const float*)d_in[10];
    const float* w1     = (const float*)d_in[11];
    const float* b1     = (const float*)d_in[12];
    const float* w2     = (const float*)d_in[13];
    const float* b2     = (const float*)d_in[14];
    float* out = (float*)d_out;           // fp32 output; also doubles as x1 buffer

    // ws layout = R12 (Pp 2*TC, Pm 4*TC overlaid)
    char* base = (char*)d_ws;
    bf16* wq_bf = (bf16*)base;                 // 1152x384
    bf16* wp_bf = wq_bf + 442368;              // 384x384
    bf16* w1_bf = wq_bf + 589824;              // 1536x384
    bf16* w2_bf = wq_bf + 1179648;             // 384x1536
    bf16* h      = (bf16*)(base + 3538944);
    bf16* qkv    = (bf16*)(base + 9830400);
    bf16* attn_o = (bf16*)(base + 28704768);
    bf16* m      = qkv;                        // overlays qkv+attn_o (both dead by mlp1)
    bf16* Pp     = (bf16*)(base + 34996224);   // 2*TC (proj split-K partials)
    bf16* Pm     = (bf16*)(base + 34996224);   // 4*TC (mlp2 split-K partials; Pp dead)

    prep_kernel<<<1728 + T_TOK/4, 256, 0, stream>>>(
        qkv_w, proj_w, w1, w2, wq_bf, x, ln1_w, ln1_b, h);
    gemm_bt<EPI_QKV, 384, 1, 9, bf16><<<64*9, 512, 0, stream>>>(
        h, wq_bf, nullptr, qkv, T_TOK, 1152);
    attn_kernel<<<768, 256, 0, stream>>>(
        qkv, qkv + TC, qkv + 2*TC, alpha, beta, gamma, attn_o);
    gemm_bt<EPI_NONE, 384, 2, 3, bf16><<<64*3*2, 512, 0, stream>>>(
        attn_o, wp_bf, nullptr, Pp, T_TOK, DIMC);
    ln2_fused<<<T_TOK/4, 256, 0, stream>>>(x, Pp, Pp + TC, proj_b, ln2_w, ln2_b, out, h);
    gemm_bt<EPI_GELU, 384, 1, 12, bf16><<<64*12, 512, 0, stream>>>(
        h, w1_bf, b1, m, T_TOK, MLPD);
    gemm_bt<EPI_NONE, 1536, 4, 3, bf16><<<64*3*4, 512, 0, stream>>>(
        m, w2_bf, nullptr, Pm, T_TOK, DIMC);
    reduce4<<<TC/4/256, 256, 0, stream>>>(out, Pm, Pm + TC, Pm + 2*TC, Pm + 3*TC, b2);
}